// Round 1
// baseline (1128.452 us; speedup 1.0000x reference)
//
#include <hip/hip_runtime.h>

#define N_NODES 50000
#define N_EDGES 800000
#define IN_C 128
#define HID 32
#define HC 128
#define OUT_C 16
#define NGRAPH 64
#define NPB 8   // nodes per block in node GEMM (50000 % 8 == 0 -> 6250 blocks)

// ---------------- CSR build ----------------
__global__ void k_hist(const int* __restrict__ tgt, int* __restrict__ deg) {
  int i = blockIdx.x * blockDim.x + threadIdx.x;
  if (i < N_EDGES) atomicAdd(&deg[tgt[i]], 1);
}

__global__ __launch_bounds__(1024) void k_scan(const int* __restrict__ deg,
                                               int* __restrict__ offs,
                                               int* __restrict__ cursor) {
  __shared__ int sm[1024];
  __shared__ int carry_s;
  if (threadIdx.x == 0) { carry_s = 0; offs[0] = 0; }
  __syncthreads();
  for (int base = 0; base < N_NODES; base += 1024) {
    int i = base + threadIdx.x;
    int v = (i < N_NODES) ? deg[i] : 0;
    sm[threadIdx.x] = v;
    __syncthreads();
    for (int off = 1; off < 1024; off <<= 1) {
      int t = (threadIdx.x >= off) ? sm[threadIdx.x - off] : 0;
      __syncthreads();
      sm[threadIdx.x] += t;
      __syncthreads();
    }
    int incl = sm[threadIdx.x] + carry_s;
    if (i < N_NODES) { offs[i + 1] = incl; cursor[i] = incl - v; }
    __syncthreads();
    if (threadIdx.x == 1023) carry_s = incl;
    __syncthreads();
  }
}

__global__ void k_scatter(const int* __restrict__ src, const int* __restrict__ tgt,
                          int* __restrict__ cursor, int* __restrict__ srcs,
                          int* __restrict__ eids) {
  int i = blockIdx.x * blockDim.x + threadIdx.x;
  if (i < N_EDGES) {
    int pos = atomicAdd(&cursor[tgt[i]], 1);
    srcs[pos] = src[i];
    eids[pos] = i;
  }
}

// ---------------- node GEMM: qn/kn/vn/sk = x@W+b, plus p = f(qn, we) ----------------
// p[n, h*32+j] = sum_{d<32} qn[n, h*32+d] * we[j, h*32+d]
__global__ __launch_bounds__(128) void k_node_gemm(
    const float* __restrict__ xin,
    const float* __restrict__ wq, const float* __restrict__ bq,
    const float* __restrict__ wk, const float* __restrict__ bk,
    const float* __restrict__ wv, const float* __restrict__ bv,
    const float* __restrict__ ws, const float* __restrict__ bs,
    const float* __restrict__ we,
    float* __restrict__ qn, float* __restrict__ kn, float* __restrict__ vn,
    float* __restrict__ sk, float* __restrict__ p) {
  int c = threadIdx.x;           // output column 0..127
  int n0 = blockIdx.x * NPB;
  float aq[NPB], ak[NPB], av[NPB], as_[NPB];
#pragma unroll
  for (int i = 0; i < NPB; ++i) { aq[i] = 0.f; ak[i] = 0.f; av[i] = 0.f; as_[i] = 0.f; }
  for (int d = 0; d < IN_C; ++d) {
    float wqv = wq[d * HC + c];
    float wkv = wk[d * HC + c];
    float wvv = wv[d * HC + c];
    float wsv = ws[d * HC + c];
#pragma unroll
    for (int i = 0; i < NPB; ++i) {
      float xv = xin[(n0 + i) * IN_C + d];   // wave-uniform -> scalar load
      aq[i] = fmaf(xv, wqv, aq[i]);
      ak[i] = fmaf(xv, wkv, ak[i]);
      av[i] = fmaf(xv, wvv, av[i]);
      as_[i] = fmaf(xv, wsv, as_[i]);
    }
  }
  __shared__ float qs[NPB][HC];
#pragma unroll
  for (int i = 0; i < NPB; ++i) {
    int n = n0 + i;
    float q = aq[i] + bq[c];
    qn[n * HC + c] = q;
    qs[i][c] = q;
    kn[n * HC + c] = ak[i] + bk[c];
    vn[n * HC + c] = av[i] + bv[c];
    sk[n * HC + c] = as_[i] + bs[c];
  }
  __syncthreads();
  int hb = (c >> 5) << 5;   // head base of column c
  int j = c & 31;
  float acc[NPB];
#pragma unroll
  for (int i = 0; i < NPB; ++i) acc[i] = 0.f;
  for (int d = 0; d < 32; ++d) {
    float wev = we[j * HC + hb + d];
#pragma unroll
    for (int i = 0; i < NPB; ++i) acc[i] = fmaf(qs[i][hb + d], wev, acc[i]);
  }
#pragma unroll
  for (int i = 0; i < NPB; ++i) p[(n0 + i) * HC + c] = acc[i];
}

// ---------------- edge attention: one wave per target node, online softmax ----------------
__global__ __launch_bounds__(64) void k_edge_attn(
    const int* __restrict__ offs, const int* __restrict__ srcs,
    const int* __restrict__ eids, const float* __restrict__ ea,
    const float* __restrict__ qn, const float* __restrict__ kn,
    const float* __restrict__ vn, const float* __restrict__ sk,
    const float* __restrict__ p, const float* __restrict__ we,
    float* __restrict__ out) {
  int t = blockIdx.x;
  int lane = threadIdx.x;
  int f0 = lane, f1 = lane + 64;
  int e0 = offs[t], e1 = offs[t + 1];
  float q0 = qn[t * HC + f0], q1 = qn[t * HC + f1];
  float p0 = p[t * HC + f0], p1 = p[t * HC + f1];
  const float inv_sqrt = 0.17677669529663687f;  // 1/sqrt(32)
  float m0 = -1e30f, m1 = -1e30f, den0 = 0.f, den1 = 0.f;
  float acc0 = 0.f, acc1 = 0.f, t0 = 0.f, t1 = 0.f;
  for (int idx = e0; idx < e1; ++idx) {
    int s = srcs[idx];       // wave-uniform
    int eid = eids[idx];
    float eav = ea[eid * HID + (lane & 31)];
    float part0 = fmaf(q0, kn[s * HC + f0], p0 * eav);
    float part1 = fmaf(q1, kn[s * HC + f1], p1 * eav);
#pragma unroll
    for (int off = 16; off > 0; off >>= 1) {
      part0 += __shfl_xor(part0, off, 64);
      part1 += __shfl_xor(part1, off, 64);
    }
    float a0 = part0 * inv_sqrt;   // head (lane<32?0:1)
    float a1 = part1 * inv_sqrt;   // head (lane<32?2:3)
    float v0 = vn[s * HC + f0], v1 = vn[s * HC + f1];
    float nm0 = fmaxf(m0, a0);
    float sc0 = __expf(m0 - nm0);
    float w0 = __expf(a0 - nm0);
    m0 = nm0;
    den0 = fmaf(den0, sc0, w0);
    acc0 = fmaf(acc0, sc0, w0 * v0);
    t0 = fmaf(t0, sc0, w0 * eav);
    float nm1 = fmaxf(m1, a1);
    float sc1 = __expf(m1 - nm1);
    float w1 = __expf(a1 - nm1);
    m1 = nm1;
    den1 = fmaf(den1, sc1, w1);
    acc1 = fmaf(acc1, sc1, w1 * v1);
    t1 = fmaf(t1, sc1, w1 * eav);
  }
  __shared__ float tl[HC];
  tl[f0] = t0;
  tl[f1] = t1;
  __syncthreads();
  int hb0 = (lane >> 5) << 5;
  int hb1 = 64 + hb0;
  float fix0 = 0.f, fix1 = 0.f;
  for (int j = 0; j < 32; ++j) {
    fix0 = fmaf(tl[hb0 + j], we[j * HC + f0], fix0);
    fix1 = fmaf(tl[hb1 + j], we[j * HC + f1], fix1);
  }
  float o0 = 0.f, o1 = 0.f;
  if (e1 > e0) { o0 = (acc0 + fix0) / den0; o1 = (acc1 + fix1) / den1; }
  o0 += sk[t * HC + f0];
  o1 += sk[t * HC + f1];
  o0 = o0 > 0.f ? o0 : __expf(o0) - 1.f;   // ELU
  o1 = o1 > 0.f ? o1 : __expf(o1) - 1.f;
  out[t * HC + f0] = o0;
  out[t * HC + f1] = o1;
}

// ---------------- global mean pool (batch sorted) ----------------
__global__ __launch_bounds__(128) void k_pool(const float* __restrict__ h,
                                              const int* __restrict__ batch,
                                              float* __restrict__ pooled) {
  int b = blockIdx.x;
  int c = threadIdx.x;
  int lo = 0, hi = N_NODES;
  while (lo < hi) { int mid = (lo + hi) >> 1; if (batch[mid] < b) lo = mid + 1; else hi = mid; }
  int start = lo;
  lo = 0; hi = N_NODES;
  while (lo < hi) { int mid = (lo + hi) >> 1; if (batch[mid] <= b) lo = mid + 1; else hi = mid; }
  int end = lo;
  float s = 0.f;
  for (int n = start; n < end; ++n) s += h[n * HC + c];
  float cnt = (float)(end - start);
  pooled[b * HC + c] = s / fmaxf(cnt, 1.0f);
}

// ---------------- classifier + log_softmax ----------------
__global__ __launch_bounds__(1024) void k_classify(const float* __restrict__ pooled,
                                                   const float* __restrict__ wlin,
                                                   const float* __restrict__ blin,
                                                   float* __restrict__ out) {
  int tid = threadIdx.x;           // 1024 = 64 graphs x 16 classes
  int b = tid >> 4, o = tid & 15;
  float acc = blin[o];
  for (int d = 0; d < HC; ++d) acc = fmaf(pooled[b * HC + d], wlin[d * OUT_C + o], acc);
  float mx = acc;
#pragma unroll
  for (int off = 8; off > 0; off >>= 1) mx = fmaxf(mx, __shfl_xor(mx, off, 64));
  float ex = __expf(acc - mx);
  float sum = ex;
#pragma unroll
  for (int off = 8; off > 0; off >>= 1) sum += __shfl_xor(sum, off, 64);
  out[tid] = acc - mx - logf(sum);
}

extern "C" void kernel_launch(void* const* d_in, const int* in_sizes, int n_in,
                              void* d_out, int out_size, void* d_ws, size_t ws_size,
                              hipStream_t stream) {
  const float* x = (const float*)d_in[0];
  const int* ei = (const int*)d_in[1];
  const float* ea = (const float*)d_in[2];
  const int* batch = (const int*)d_in[3];
  const float* wq1 = (const float*)d_in[4];  const float* bq1 = (const float*)d_in[5];
  const float* wk1 = (const float*)d_in[6];  const float* bk1 = (const float*)d_in[7];
  const float* wv1 = (const float*)d_in[8];  const float* bv1 = (const float*)d_in[9];
  const float* we1 = (const float*)d_in[10];
  const float* ws1 = (const float*)d_in[11]; const float* bs1 = (const float*)d_in[12];
  const float* wq2 = (const float*)d_in[13]; const float* bq2 = (const float*)d_in[14];
  const float* wk2 = (const float*)d_in[15]; const float* bk2 = (const float*)d_in[16];
  const float* wv2 = (const float*)d_in[17]; const float* bv2 = (const float*)d_in[18];
  const float* we2 = (const float*)d_in[19];
  const float* ws2 = (const float*)d_in[20]; const float* bs2 = (const float*)d_in[21];
  const float* wlin = (const float*)d_in[22]; const float* blin = (const float*)d_in[23];

  const int* srcI = ei;             // edge_index[0]
  const int* tgtI = ei + N_EDGES;   // edge_index[1]

  char* wsb = (char*)d_ws;
  size_t off = 0;
  auto alloc = [&](size_t bytes) -> void* {
    void* ptr = wsb + off;
    off += (bytes + 255) & ~(size_t)255;
    return ptr;
  };
  float* qn = (float*)alloc((size_t)N_NODES * HC * 4);
  float* kn = (float*)alloc((size_t)N_NODES * HC * 4);
  float* vn = (float*)alloc((size_t)N_NODES * HC * 4);
  float* sk = (float*)alloc((size_t)N_NODES * HC * 4);
  float* p  = (float*)alloc((size_t)N_NODES * HC * 4);
  float* h  = (float*)alloc((size_t)N_NODES * HC * 4);
  float* pooled = (float*)alloc((size_t)NGRAPH * HC * 4);
  int* deg    = (int*)alloc((size_t)N_NODES * 4);
  int* offs   = (int*)alloc((size_t)(N_NODES + 1) * 4);
  int* cursor = (int*)alloc((size_t)N_NODES * 4);
  int* srcs   = (int*)alloc((size_t)N_EDGES * 4);
  int* eids   = (int*)alloc((size_t)N_EDGES * 4);

  // CSR build (shared by both layers)
  hipMemsetAsync(deg, 0, (size_t)N_NODES * 4, stream);
  k_hist<<<(N_EDGES + 255) / 256, 256, 0, stream>>>(tgtI, deg);
  k_scan<<<1, 1024, 0, stream>>>(deg, offs, cursor);
  k_scatter<<<(N_EDGES + 255) / 256, 256, 0, stream>>>(srcI, tgtI, cursor, srcs, eids);

  // Layer 1
  k_node_gemm<<<N_NODES / NPB, 128, 0, stream>>>(x, wq1, bq1, wk1, bk1, wv1, bv1,
                                                 ws1, bs1, we1, qn, kn, vn, sk, p);
  k_edge_attn<<<N_NODES, 64, 0, stream>>>(offs, srcs, eids, ea, qn, kn, vn, sk, p, we1, h);

  // Layer 2
  k_node_gemm<<<N_NODES / NPB, 128, 0, stream>>>(h, wq2, bq2, wk2, bk2, wv2, bv2,
                                                 ws2, bs2, we2, qn, kn, vn, sk, p);
  k_edge_attn<<<N_NODES, 64, 0, stream>>>(offs, srcs, eids, ea, qn, kn, vn, sk, p, we2, h);

  // Pool + classify
  k_pool<<<NGRAPH, 128, 0, stream>>>(h, batch, pooled);
  k_classify<<<1, 1024, 0, stream>>>(pooled, wlin, blin, (float*)d_out);
}

// Round 2
// 935.783 us; speedup vs baseline: 1.2059x; 1.2059x over previous
//
#include <hip/hip_runtime.h>

#define N_NODES 50000
#define N_EDGES 800000
#define IN_C 128
#define HID 32
#define HC 128
#define OUT_C 16
#define NGRAPH 64
#define NPB 8    // nodes per block in node GEMM
#define PNB 125  // nodes per block in pool (50000/125 = 400 blocks)

// ---------------- CSR build ----------------
__global__ void k_hist(const int* __restrict__ tgt, int* __restrict__ deg) {
  int i = blockIdx.x * blockDim.x + threadIdx.x;
  if (i < N_EDGES) atomicAdd(&deg[tgt[i]], 1);
}

// single-block scan, shfl-based (3 barriers per 1024-tile instead of 20)
__global__ __launch_bounds__(1024) void k_scan(const int* __restrict__ deg,
                                               int* __restrict__ offs,
                                               int* __restrict__ cursor) {
  __shared__ int wsum[16];
  __shared__ int carry_s;
  int lane = threadIdx.x & 63, wid = threadIdx.x >> 6;
  if (threadIdx.x == 0) { carry_s = 0; offs[0] = 0; }
  __syncthreads();
  for (int base = 0; base < N_NODES; base += 1024) {
    int i = base + threadIdx.x;
    int v = (i < N_NODES) ? deg[i] : 0;
    int x = v;
#pragma unroll
    for (int off = 1; off < 64; off <<= 1) {
      int t = __shfl_up(x, off, 64);
      if (lane >= off) x += t;
    }
    if (lane == 63) wsum[wid] = x;
    __syncthreads();
    if (wid == 0 && lane < 16) {
      int s = wsum[lane];
#pragma unroll
      for (int off = 1; off < 16; off <<= 1) {
        int t = __shfl_up(s, off, 64);
        if (lane >= off) s += t;
      }
      wsum[lane] = s;
    }
    __syncthreads();
    int add = (wid > 0 ? wsum[wid - 1] : 0) + carry_s;
    int incl = x + add;
    if (i < N_NODES) { offs[i + 1] = incl; cursor[i] = incl - v; }
    __syncthreads();
    if (threadIdx.x == 1023) carry_s = incl;
    __syncthreads();
  }
}

__global__ void k_scatter(const int* __restrict__ src, const int* __restrict__ tgt,
                          int* __restrict__ cursor, int* __restrict__ srcs,
                          int* __restrict__ eids) {
  int i = blockIdx.x * blockDim.x + threadIdx.x;
  if (i < N_EDGES) {
    int pos = atomicAdd(&cursor[tgt[i]], 1);
    srcs[pos] = src[i];
    eids[pos] = i;
  }
}

// ---------------- node GEMM: qn/kn/vn/sk = x@W+b, plus p = f(qn, we) ----------------
__global__ __launch_bounds__(128) void k_node_gemm(
    const float* __restrict__ xin,
    const float* __restrict__ wq, const float* __restrict__ bq,
    const float* __restrict__ wk, const float* __restrict__ bk,
    const float* __restrict__ wv, const float* __restrict__ bv,
    const float* __restrict__ ws, const float* __restrict__ bs,
    const float* __restrict__ we,
    float* __restrict__ qn, float* __restrict__ kn, float* __restrict__ vn,
    float* __restrict__ sk, float* __restrict__ p) {
  int c = threadIdx.x;           // output column 0..127
  int n0 = blockIdx.x * NPB;
  float aq[NPB], ak[NPB], av[NPB], as_[NPB];
#pragma unroll
  for (int i = 0; i < NPB; ++i) { aq[i] = 0.f; ak[i] = 0.f; av[i] = 0.f; as_[i] = 0.f; }
  for (int d = 0; d < IN_C; ++d) {
    float wqv = wq[d * HC + c];
    float wkv = wk[d * HC + c];
    float wvv = wv[d * HC + c];
    float wsv = ws[d * HC + c];
#pragma unroll
    for (int i = 0; i < NPB; ++i) {
      float xv = xin[(n0 + i) * IN_C + d];   // wave-uniform -> scalar load
      aq[i] = fmaf(xv, wqv, aq[i]);
      ak[i] = fmaf(xv, wkv, ak[i]);
      av[i] = fmaf(xv, wvv, av[i]);
      as_[i] = fmaf(xv, wsv, as_[i]);
    }
  }
  __shared__ float qs[NPB][HC];
#pragma unroll
  for (int i = 0; i < NPB; ++i) {
    int n = n0 + i;
    float q = aq[i] + bq[c];
    qn[n * HC + c] = q;
    qs[i][c] = q;
    kn[n * HC + c] = ak[i] + bk[c];
    vn[n * HC + c] = av[i] + bv[c];
    sk[n * HC + c] = as_[i] + bs[c];
  }
  __syncthreads();
  int hb = (c >> 5) << 5;   // head base of column c
  int j = c & 31;
  float acc[NPB];
#pragma unroll
  for (int i = 0; i < NPB; ++i) acc[i] = 0.f;
  for (int d = 0; d < 32; ++d) {
    float wev = we[j * HC + hb + d];
#pragma unroll
    for (int i = 0; i < NPB; ++i) acc[i] = fmaf(qs[i][hb + d], wev, acc[i]);
  }
#pragma unroll
  for (int i = 0; i < NPB; ++i) p[(n0 + i) * HC + c] = acc[i];
}

// ---------------- edge attention: one wave per target node, online softmax ----------------
__global__ __launch_bounds__(64) void k_edge_attn(
    const int* __restrict__ offs, const int* __restrict__ srcs,
    const int* __restrict__ eids, const float* __restrict__ ea,
    const float* __restrict__ qn, const float* __restrict__ kn,
    const float* __restrict__ vn, const float* __restrict__ sk,
    const float* __restrict__ p, const float* __restrict__ we,
    float* __restrict__ out) {
  int t = blockIdx.x;
  int lane = threadIdx.x;
  int f0 = lane, f1 = lane + 64;
  int e0 = offs[t], e1 = offs[t + 1];
  float q0 = qn[t * HC + f0], q1 = qn[t * HC + f1];
  float p0 = p[t * HC + f0], p1 = p[t * HC + f1];
  const float inv_sqrt = 0.17677669529663687f;  // 1/sqrt(32)
  float m0 = -1e30f, m1 = -1e30f, den0 = 0.f, den1 = 0.f;
  float acc0 = 0.f, acc1 = 0.f, t0 = 0.f, t1 = 0.f;
  for (int idx = e0; idx < e1; ++idx) {
    int s = srcs[idx];       // wave-uniform
    int eid = eids[idx];
    float eav = ea[eid * HID + (lane & 31)];
    float part0 = fmaf(q0, kn[s * HC + f0], p0 * eav);
    float part1 = fmaf(q1, kn[s * HC + f1], p1 * eav);
#pragma unroll
    for (int off = 16; off > 0; off >>= 1) {
      part0 += __shfl_xor(part0, off, 64);
      part1 += __shfl_xor(part1, off, 64);
    }
    float a0 = part0 * inv_sqrt;   // head (lane<32?0:1)
    float a1 = part1 * inv_sqrt;   // head (lane<32?2:3)
    float v0 = vn[s * HC + f0], v1 = vn[s * HC + f1];
    float nm0 = fmaxf(m0, a0);
    float sc0 = __expf(m0 - nm0);
    float w0 = __expf(a0 - nm0);
    m0 = nm0;
    den0 = fmaf(den0, sc0, w0);
    acc0 = fmaf(acc0, sc0, w0 * v0);
    t0 = fmaf(t0, sc0, w0 * eav);
    float nm1 = fmaxf(m1, a1);
    float sc1 = __expf(m1 - nm1);
    float w1 = __expf(a1 - nm1);
    m1 = nm1;
    den1 = fmaf(den1, sc1, w1);
    acc1 = fmaf(acc1, sc1, w1 * v1);
    t1 = fmaf(t1, sc1, w1 * eav);
  }
  __shared__ float tl[HC];
  tl[f0] = t0;
  tl[f1] = t1;
  __syncthreads();
  int hb0 = (lane >> 5) << 5;
  int hb1 = 64 + hb0;
  float fix0 = 0.f, fix1 = 0.f;
  for (int j = 0; j < 32; ++j) {
    fix0 = fmaf(tl[hb0 + j], we[j * HC + f0], fix0);
    fix1 = fmaf(tl[hb1 + j], we[j * HC + f1], fix1);
  }
  float o0 = 0.f, o1 = 0.f;
  if (e1 > e0) { o0 = (acc0 + fix0) / den0; o1 = (acc1 + fix1) / den1; }
  o0 += sk[t * HC + f0];
  o1 += sk[t * HC + f1];
  o0 = o0 > 0.f ? o0 : __expf(o0) - 1.f;   // ELU
  o1 = o1 > 0.f ? o1 : __expf(o1) - 1.f;
  out[t * HC + f0] = o0;
  out[t * HC + f1] = o1;
}

// ---------------- global mean pool, parallel over node chunks ----------------
// batch is sorted: accumulate in registers, atomic-flush at graph boundaries.
__global__ __launch_bounds__(128) void k_pool_sum(const float* __restrict__ h,
                                                  const int* __restrict__ batch,
                                                  float* __restrict__ psum) {
  int c = threadIdx.x;
  int n0 = blockIdx.x * PNB;
  int n1 = n0 + PNB;
  float acc = 0.f;
  int curb = batch[n0];             // wave-uniform
  for (int n = n0; n < n1; ++n) {
    int b = batch[n];
    if (b != curb) {
      atomicAdd(&psum[curb * HC + c], acc);
      acc = 0.f;
      curb = b;
    }
    acc += h[n * HC + c];
  }
  atomicAdd(&psum[curb * HC + c], acc);
}

// ---------------- classifier + log_softmax (division by count folded in) ----------------
__global__ __launch_bounds__(1024) void k_classify(const float* __restrict__ psum,
                                                   const int* __restrict__ batch,
                                                   const float* __restrict__ wlin,
                                                   const float* __restrict__ blin,
                                                   float* __restrict__ out) {
  int tid = threadIdx.x;           // 1024 = 64 graphs x 16 classes
  int b = tid >> 4, o = tid & 15;
  // count nodes in graph b via binary search (batch sorted)
  int lo = 0, hi = N_NODES;
  while (lo < hi) { int mid = (lo + hi) >> 1; if (batch[mid] < b) lo = mid + 1; else hi = mid; }
  int start = lo;
  lo = 0; hi = N_NODES;
  while (lo < hi) { int mid = (lo + hi) >> 1; if (batch[mid] <= b) lo = mid + 1; else hi = mid; }
  float cnt = fmaxf((float)(lo - start), 1.0f);
  float dot = 0.f;
  for (int d = 0; d < HC; ++d) dot = fmaf(psum[b * HC + d], wlin[d * OUT_C + o], dot);
  float acc = dot / cnt + blin[o];
  float mx = acc;
#pragma unroll
  for (int off = 8; off > 0; off >>= 1) mx = fmaxf(mx, __shfl_xor(mx, off, 64));
  float ex = __expf(acc - mx);
  float sum = ex;
#pragma unroll
  for (int off = 8; off > 0; off >>= 1) sum += __shfl_xor(sum, off, 64);
  out[tid] = acc - mx - logf(sum);
}

extern "C" void kernel_launch(void* const* d_in, const int* in_sizes, int n_in,
                              void* d_out, int out_size, void* d_ws, size_t ws_size,
                              hipStream_t stream) {
  const float* x = (const float*)d_in[0];
  const int* ei = (const int*)d_in[1];
  const float* ea = (const float*)d_in[2];
  const int* batch = (const int*)d_in[3];
  const float* wq1 = (const float*)d_in[4];  const float* bq1 = (const float*)d_in[5];
  const float* wk1 = (const float*)d_in[6];  const float* bk1 = (const float*)d_in[7];
  const float* wv1 = (const float*)d_in[8];  const float* bv1 = (const float*)d_in[9];
  const float* we1 = (const float*)d_in[10];
  const float* ws1 = (const float*)d_in[11]; const float* bs1 = (const float*)d_in[12];
  const float* wq2 = (const float*)d_in[13]; const float* bq2 = (const float*)d_in[14];
  const float* wk2 = (const float*)d_in[15]; const float* bk2 = (const float*)d_in[16];
  const float* wv2 = (const float*)d_in[17]; const float* bv2 = (const float*)d_in[18];
  const float* we2 = (const float*)d_in[19];
  const float* ws2 = (const float*)d_in[20]; const float* bs2 = (const float*)d_in[21];
  const float* wlin = (const float*)d_in[22]; const float* blin = (const float*)d_in[23];

  const int* srcI = ei;             // edge_index[0]
  const int* tgtI = ei + N_EDGES;   // edge_index[1]

  char* wsb = (char*)d_ws;
  size_t off = 0;
  auto alloc = [&](size_t bytes) -> void* {
    void* ptr = wsb + off;
    off += (bytes + 255) & ~(size_t)255;
    return ptr;
  };
  float* qn = (float*)alloc((size_t)N_NODES * HC * 4);
  float* kn = (float*)alloc((size_t)N_NODES * HC * 4);
  float* vn = (float*)alloc((size_t)N_NODES * HC * 4);
  float* sk = (float*)alloc((size_t)N_NODES * HC * 4);
  float* p  = (float*)alloc((size_t)N_NODES * HC * 4);
  float* h  = (float*)alloc((size_t)N_NODES * HC * 4);
  float* psum = (float*)alloc((size_t)NGRAPH * HC * 4);
  int* deg    = (int*)alloc((size_t)N_NODES * 4);
  int* offs   = (int*)alloc((size_t)(N_NODES + 1) * 4);
  int* cursor = (int*)alloc((size_t)N_NODES * 4);
  int* srcs   = (int*)alloc((size_t)N_EDGES * 4);
  int* eids   = (int*)alloc((size_t)N_EDGES * 4);

  // CSR build (shared by both layers)
  hipMemsetAsync(deg, 0, (size_t)N_NODES * 4, stream);
  k_hist<<<(N_EDGES + 255) / 256, 256, 0, stream>>>(tgtI, deg);
  k_scan<<<1, 1024, 0, stream>>>(deg, offs, cursor);
  k_scatter<<<(N_EDGES + 255) / 256, 256, 0, stream>>>(srcI, tgtI, cursor, srcs, eids);

  // Layer 1
  k_node_gemm<<<N_NODES / NPB, 128, 0, stream>>>(x, wq1, bq1, wk1, bk1, wv1, bv1,
                                                 ws1, bs1, we1, qn, kn, vn, sk, p);
  k_edge_attn<<<N_NODES, 64, 0, stream>>>(offs, srcs, eids, ea, qn, kn, vn, sk, p, we1, h);

  // Layer 2
  k_node_gemm<<<N_NODES / NPB, 128, 0, stream>>>(h, wq2, bq2, wk2, bk2, wv2, bv2,
                                                 ws2, bs2, we2, qn, kn, vn, sk, p);
  k_edge_attn<<<N_NODES, 64, 0, stream>>>(offs, srcs, eids, ea, qn, kn, vn, sk, p, we2, h);

  // Pool + classify
  hipMemsetAsync(psum, 0, (size_t)NGRAPH * HC * 4, stream);
  k_pool_sum<<<N_NODES / PNB, 128, 0, stream>>>(h, batch, psum);
  k_classify<<<1, 1024, 0, stream>>>(psum, batch, wlin, blin, (float*)d_out);
}